// Round 1
// baseline (786.831 us; speedup 1.0000x reference)
//
#include <hip/hip_runtime.h>
#include <math.h>

// Problem constants
namespace {
constexpr int Dd = 768;
constexpr int Rr = 3;
constexpr int NEe = 4;
constexpr int Bb = 8;
constexpr int Nn = 16384;   // = 128*128
constexpr int Hh = 128;
constexpr int Wc = 128;
constexpr int NPLANE = Bb * Rr;        // 24
constexpr int ROWS = Bb * Nn;          // 131072
}

// ---------------------------------------------------------------------------
// Kernel 1: xr = x @ Wd + bd  -> stored as feat[(b*3+r)*16384 + n]
// Wave-per-row. Wd slice held in per-lane registers (no LDS bank conflicts).
// ---------------------------------------------------------------------------
__global__ __launch_bounds__(256) void k_xr(const float* __restrict__ x,
                                            const float* __restrict__ Wd,
                                            const float* __restrict__ bd,
                                            float* __restrict__ feat) {
  const int lane = threadIdx.x & 63;
  const int wave = (blockIdx.x << 2) + (threadIdx.x >> 6);
  const int nwaves = gridDim.x << 2;

  // lane handles elements e = i*256 + lane*4 + c, i in [0,3), c in [0,4)
  float w[3][4][3];
#pragma unroll
  for (int i = 0; i < 3; ++i) {
    const int e0 = i * 256 + lane * 4;
#pragma unroll
    for (int c = 0; c < 4; ++c)
#pragma unroll
      for (int r = 0; r < 3; ++r) w[i][c][r] = Wd[(e0 + c) * 3 + r];
  }
  const float b0 = bd[0], b1 = bd[1], b2 = bd[2];

  for (int row = wave; row < ROWS; row += nwaves) {
    const float4* xr4 = (const float4*)(x + (size_t)row * Dd);
    float a0 = 0.f, a1 = 0.f, a2 = 0.f;
#pragma unroll
    for (int i = 0; i < 3; ++i) {
      const float4 v = xr4[i * 64 + lane];
      a0 += v.x * w[i][0][0] + v.y * w[i][1][0] + v.z * w[i][2][0] + v.w * w[i][3][0];
      a1 += v.x * w[i][0][1] + v.y * w[i][1][1] + v.z * w[i][2][1] + v.w * w[i][3][1];
      a2 += v.x * w[i][0][2] + v.y * w[i][1][2] + v.z * w[i][2][2] + v.w * w[i][3][2];
    }
#pragma unroll
    for (int off = 32; off; off >>= 1) {
      a0 += __shfl_xor(a0, off);
      a1 += __shfl_xor(a1, off);
      a2 += __shfl_xor(a2, off);
    }
    if (lane == 0) {
      const int b = row >> 14, n = row & 16383;
      feat[((b * 3 + 0) << 14) + n] = a0 + b0;
      feat[((b * 3 + 1) << 14) + n] = a1 + b1;
      feat[((b * 3 + 2) << 14) + n] = a2 + b2;
    }
  }
}

// ---------------------------------------------------------------------------
// Kernel 2: gating. One block per batch b. Reduce feat planes -> xa,
// then thread 0 computes noisy-top2 softmax gate G[b][0..3].
// ---------------------------------------------------------------------------
__global__ __launch_bounds__(256) void k_gate(const float* __restrict__ feat,
                                              const float* __restrict__ noise,
                                              const float* __restrict__ Wg,
                                              const float* __restrict__ Wn,
                                              float* __restrict__ G) {
  const int b = blockIdx.x;
  const int t = threadIdx.x;
  float s0 = 0.f, s1 = 0.f, s2 = 0.f;
  for (int n = t; n < Nn; n += 256) {
    s0 += feat[((b * 3 + 0) << 14) + n];
    s1 += feat[((b * 3 + 1) << 14) + n];
    s2 += feat[((b * 3 + 2) << 14) + n];
  }
  __shared__ float sm0[256], sm1[256], sm2[256];
  sm0[t] = s0; sm1[t] = s1; sm2[t] = s2;
  __syncthreads();
  for (int step = 128; step; step >>= 1) {
    if (t < step) {
      sm0[t] += sm0[t + step];
      sm1[t] += sm1[t + step];
      sm2[t] += sm2[t + step];
    }
    __syncthreads();
  }
  if (t == 0) {
    const float inv = 1.0f / (float)Nn;
    float xa[3] = {sm0[0] * inv, sm1[0] * inv, sm2[0] * inv};
    float hlog[NEe];
#pragma unroll
    for (int e = 0; e < NEe; ++e) {
      float hg = xa[0] * Wg[0 * NEe + e] + xa[1] * Wg[1 * NEe + e] + xa[2] * Wg[2 * NEe + e];
      float hn = xa[0] * Wn[0 * NEe + e] + xa[1] * Wn[1 * NEe + e] + xa[2] * Wn[2 * NEe + e];
      float sp = (hn > 20.f) ? hn : log1pf(expf(hn));   // softplus
      hlog[e] = hg + noise[b * NEe + e] * sp;
    }
    // top-2 (first-index tie-break, matches lax.top_k)
    int i1 = 0;
#pragma unroll
    for (int e = 1; e < NEe; ++e) if (hlog[e] > hlog[i1]) i1 = e;
    int i2 = -1;
#pragma unroll
    for (int e = 0; e < NEe; ++e) {
      if (e == i1) continue;
      if (i2 < 0 || hlog[e] > hlog[i2]) i2 = e;
    }
    const float m = hlog[i1];
    const float z = expf(hlog[i1] - m) + expf(hlog[i2] - m);
#pragma unroll
    for (int e = 0; e < NEe; ++e)
      G[b * NEe + e] = (e == i1 || e == i2) ? expf(hlog[e] - m) / z : 0.f;
  }
}

// ---------------------------------------------------------------------------
// Kernel 3: fused (downsample -> depthwise 3x3 conv + bias) for all 4 scales.
// Downsample by F in {2,4,8} is exactly avg of 2x2 block at rows
// {F*i+F/2-1, F*i+F/2} (half-pixel linear, no antialias, all taps interior).
// ---------------------------------------------------------------------------
__global__ __launch_bounds__(256) void k_conv(const float* __restrict__ feat,
                                              const float* __restrict__ dwk,
                                              const float* __restrict__ dwb,
                                              float* __restrict__ conv0,
                                              float* __restrict__ conv1,
                                              float* __restrict__ conv2,
                                              float* __restrict__ conv3) {
  int t = blockIdx.x * 256 + threadIdx.x;
  const int S0 = NPLANE * 16384;
  const int S1 = NPLANE * 4096;
  const int S2 = NPLANE * 1024;
  const int S3 = NPLANE * 256;

  int scale, plane, pix, hs;
  float* outp;
  if (t < S0) { scale = 0; plane = t >> 14; pix = t & 16383; hs = 128; outp = conv0; }
  else if ((t -= S0) < S1) { scale = 1; plane = t >> 12; pix = t & 4095; hs = 64; outp = conv1; }
  else if ((t -= S1) < S2) { scale = 2; plane = t >> 10; pix = t & 1023; hs = 32; outp = conv2; }
  else if ((t -= S2) < S3) { scale = 3; plane = t >> 8;  pix = t & 255;  hs = 16; outp = conv3; }
  else return;

  const int r = plane % 3;
  const float* f = feat + ((size_t)plane << 14);
  const int y = pix / hs, xx = pix % hs;
  float acc = dwb[r];

  if (scale == 0) {
#pragma unroll
    for (int dy = 0; dy < 3; ++dy) {
      const int iy = y + dy - 1;
      if (iy < 0 || iy >= 128) continue;
#pragma unroll
      for (int dx = 0; dx < 3; ++dx) {
        const int ix = xx + dx - 1;
        if (ix < 0 || ix >= 128) continue;
        acc += dwk[r * 9 + dy * 3 + dx] * f[iy * 128 + ix];
      }
    }
  } else {
    const int F = 128 / hs;           // 2, 4, 8
    const int off = (F >> 1) - 1;
#pragma unroll
    for (int dy = 0; dy < 3; ++dy) {
      const int i = y + dy - 1;
      if (i < 0 || i >= hs) continue;   // zero pad
      const int yA = F * i + off;
#pragma unroll
      for (int dx = 0; dx < 3; ++dx) {
        const int k2 = xx + dx - 1;
        if (k2 < 0 || k2 >= hs) continue;
        const int xA = F * k2 + off;
        const float* fp = f + yA * 128 + xA;
        const float dv = 0.25f * (fp[0] + fp[1] + fp[128] + fp[129]);
        acc += dwk[r * 9 + dy * 3 + dx] * dv;
      }
    }
  }
  outp[(size_t)plane * hs * hs + pix] = acc;
}

// half-pixel linear upsample sample with edge clamp (== jax weight-renorm)
__device__ __forceinline__ float bilerp_up(const float* __restrict__ img, int hs,
                                           int y, int x) {
  const float sc = (float)hs / 128.0f;        // exact: 0.5 / 0.25 / 0.125
  float sy = (y + 0.5f) * sc - 0.5f;
  float sx = (x + 0.5f) * sc - 0.5f;
  if (sy < 0.f) sy = 0.f;
  if (sx < 0.f) sx = 0.f;
  int y0 = (int)sy, x0 = (int)sx;
  const float fy = sy - y0, fx = sx - x0;
  int y1 = y0 + 1 < hs ? y0 + 1 : hs - 1;
  int x1 = x0 + 1 < hs ? x0 + 1 : hs - 1;
  const float v00 = img[y0 * hs + x0], v01 = img[y0 * hs + x1];
  const float v10 = img[y1 * hs + x0], v11 = img[y1 * hs + x1];
  return (1.f - fy) * ((1.f - fx) * v00 + fx * v01) + fy * ((1.f - fx) * v10 + fx * v11);
}

// ---------------------------------------------------------------------------
// Kernel 4: mixed[b,n,r] = G[b,0]*conv0 + sum_j G[b,j]*upsample(convj)
// Written in (B,N,R) layout for the epilogue.
// ---------------------------------------------------------------------------
__global__ __launch_bounds__(256) void k_mix(const float* __restrict__ conv0,
                                             const float* __restrict__ conv1,
                                             const float* __restrict__ conv2,
                                             const float* __restrict__ conv3,
                                             const float* __restrict__ G,
                                             float* __restrict__ mixed) {
  const int t = blockIdx.x * 256 + threadIdx.x;
  if (t >= NPLANE * 16384) return;
  const int plane = t >> 14, pix = t & 16383;
  const int b = plane / 3, r = plane % 3;
  const int y = pix >> 7, x = pix & 127;

  const float g0 = G[b * NEe + 0], g1 = G[b * NEe + 1];
  const float g2 = G[b * NEe + 2], g3 = G[b * NEe + 3];

  float acc = g0 * conv0[((size_t)plane << 14) + pix];
  acc += g1 * bilerp_up(conv1 + (size_t)plane * 4096, 64, y, x);
  acc += g2 * bilerp_up(conv2 + (size_t)plane * 1024, 32, y, x);
  acc += g3 * bilerp_up(conv3 + (size_t)plane * 256, 16, y, x);

  mixed[((size_t)((b << 14) + pix)) * 3 + r] = acc;
}

// ---------------------------------------------------------------------------
// Kernel 5: out = x + mixed @ Wu + bu.  Wave-per-row, Wu/bu in registers.
// ---------------------------------------------------------------------------
__global__ __launch_bounds__(256) void k_out(const float* __restrict__ x,
                                             const float* __restrict__ mixed,
                                             const float* __restrict__ Wu,
                                             const float* __restrict__ bu,
                                             float* __restrict__ out) {
  const int lane = threadIdx.x & 63;
  const int wave = (blockIdx.x << 2) + (threadIdx.x >> 6);
  const int nwaves = gridDim.x << 2;

  float wu[3][4][3];  // [i][c][r] : Wu[r*768 + e]
  float bue[3][4];
#pragma unroll
  for (int i = 0; i < 3; ++i) {
    const int e0 = i * 256 + lane * 4;
#pragma unroll
    for (int c = 0; c < 4; ++c) {
#pragma unroll
      for (int r = 0; r < 3; ++r) wu[i][c][r] = Wu[r * Dd + e0 + c];
      bue[i][c] = bu[e0 + c];
    }
  }

  for (int row = wave; row < ROWS; row += nwaves) {
    const float* mp = mixed + (size_t)row * 3;
    const float m0 = mp[0], m1 = mp[1], m2 = mp[2];
    const float4* xr4 = (const float4*)(x + (size_t)row * Dd);
    float4* or4 = (float4*)(out + (size_t)row * Dd);
#pragma unroll
    for (int i = 0; i < 3; ++i) {
      const float4 v = xr4[i * 64 + lane];
      float4 o;
      o.x = v.x + m0 * wu[i][0][0] + m1 * wu[i][0][1] + m2 * wu[i][0][2] + bue[i][0];
      o.y = v.y + m0 * wu[i][1][0] + m1 * wu[i][1][1] + m2 * wu[i][1][2] + bue[i][1];
      o.z = v.z + m0 * wu[i][2][0] + m1 * wu[i][2][1] + m2 * wu[i][2][2] + bue[i][2];
      o.w = v.w + m0 * wu[i][3][0] + m1 * wu[i][3][1] + m2 * wu[i][3][2] + bue[i][3];
      or4[i * 64 + lane] = o;
    }
  }
}

// ---------------------------------------------------------------------------
extern "C" void kernel_launch(void* const* d_in, const int* in_sizes, int n_in,
                              void* d_out, int out_size, void* d_ws, size_t ws_size,
                              hipStream_t stream) {
  const float* x     = (const float*)d_in[0];
  const float* noise = (const float*)d_in[1];
  const float* Wd    = (const float*)d_in[2];
  const float* bd    = (const float*)d_in[3];
  const float* Wu    = (const float*)d_in[4];
  const float* bu    = (const float*)d_in[5];
  const float* Wg    = (const float*)d_in[6];
  const float* Wn    = (const float*)d_in[7];
  const float* dwk   = (const float*)d_in[8];
  const float* dwb   = (const float*)d_in[9];
  float* out = (float*)d_out;

  float* ws = (float*)d_ws;
  float* feat  = ws;                    // 393216
  float* conv0 = feat + 393216;         // 393216
  float* conv1 = conv0 + 393216;        // 98304
  float* conv2 = conv1 + 98304;         // 24576
  float* conv3 = conv2 + 24576;         // 6144
  float* Gbuf  = conv3 + 6144;          // 32
  float* mixed = Gbuf + 32;             // 393216
  // total ~5.24 MB of workspace

  k_xr<<<2048, 256, 0, stream>>>(x, Wd, bd, feat);
  k_gate<<<Bb, 256, 0, stream>>>(feat, noise, Wg, Wn, Gbuf);
  {
    const int total = NPLANE * (16384 + 4096 + 1024 + 256);  // 522240
    k_conv<<<(total + 255) / 256, 256, 0, stream>>>(feat, dwk, dwb,
                                                    conv0, conv1, conv2, conv3);
  }
  k_mix<<<(NPLANE * 16384 + 255) / 256, 256, 0, stream>>>(conv0, conv1, conv2,
                                                          conv3, Gbuf, mixed);
  k_out<<<2048, 256, 0, stream>>>(x, mixed, Wu, bu, out);
}